// Round 2
// baseline (2251.702 us; speedup 1.0000x reference)
//
#include <hip/hip_runtime.h>

// GlobalNet conv-GRU on MI355X — round 7.
// r6 post-mortem: M=64/wave at 5 waves/block collapsed occupancy (1.25 w/SIMD,
// ~200 VGPR live) and doubled staging -> 1618us. REVERT to r5's geometry
// (256 blocks x 640 thr, 10 waves, M=32 owned rows) and instead fuse TWO
// timesteps per launch via halo redundancy:
//   stage h_t rows l0-10..l0+41 (52) -> GEMM1 over 48 rows (3 m-frags) ->
//   h_{t+1} written back to LDS (bf16, OOB rows zero-masked; pad ch zeroed) ->
//   GEMM2 over the 32 owned rows (2 m-frags) -> h_{t+2} to global.
// Halves launches (64->32), global h round-trips, and per-step drain barriers.
// fp32 h-chain preserved: own-row h_{t+1} goes through fp32 LDS (h1l); only
// halo h_old uses bf16 (it only feeds GEMM2's bf16 A operand).

#define Bn   16
#define Tn   64
#define Ln   512
#define Cn   64
#define Hn   150
#define G3   450
#define SW   160
#define HP   160    // padded hidden
#define KCH  25     // k-chunks (32) for h GEMM (K=800)
#define KCX  10     // k-chunks for x GEMM (K=320)
#define Mtot 8192   // Bn*Ln
#define H1S  164    // h1l fp32 row stride (pad: quads hit distinct bank halves)

typedef __bf16 bf16x8 __attribute__((ext_vector_type(8)));
typedef float  f32x4  __attribute__((ext_vector_type(4)));
typedef short  s16x4  __attribute__((ext_vector_type(4)));

__device__ inline short f2bf(float f) {
  unsigned u = __builtin_bit_cast(unsigned, f);
  u += 0x7fffu + ((u >> 16) & 1u);   // RNE (finite inputs)
  return (short)(u >> 16);
}
__device__ inline float bf2f(short s) {
  unsigned u = ((unsigned)(unsigned short)s) << 16;
  return __builtin_bit_cast(float, u);
}

// Packed B layout: [nt (n/16)][kc][lane (quad*16+l16)][j (8)] shorts.
// Fragment element: B[k = kc*32+quad*8+j][n = nt*16+l16].
// n maps (seg=n/160, jl=n%160) -> orig col seg*150+jl (zero pad elsewhere).
__global__ __launch_bounds__(256) void pack_weights(const float* __restrict__ ki,
                                                    const float* __restrict__ kh,
                                                    short* __restrict__ Bx,
                                                    short* __restrict__ Bh) {
  int idx = blockIdx.x * 256 + threadIdx.x;
  if (idx < 32 * KCH * 512) {
    int j = idx & 7, lane = (idx >> 3) & 63;
    int rest = idx >> 9;
    int kc = rest % KCH, nt = rest / KCH;
    int quad = lane >> 4, l16 = lane & 15;
    int n = nt * 16 + l16, seg = n / SW, jl = n - seg * SW;
    int kk = kc / 5, jj = (kc - kk * 5) * 32 + quad * 8 + j;
    float v = (seg < 3 && jl < Hn && jj < Hn) ? kh[(kk * Hn + jj) * G3 + seg * Hn + jl] : 0.f;
    Bh[idx] = f2bf(v);
  } else {
    int r = idx - 32 * KCH * 512;
    if (r < 32 * KCX * 512) {
      int j = r & 7, lane = (r >> 3) & 63;
      int rest = r >> 9;
      int kc = rest % KCX, nt = rest / KCX;
      int quad = lane >> 4, l16 = lane & 15;
      int n = nt * 16 + l16, seg = n / SW, jl = n - seg * SW;
      int kk = kc / 2, cc = (kc - kk * 2) * 32 + quad * 8 + j;
      float v = (seg < 3 && jl < Hn) ? ki[(kk * Cn + cc) * G3 + seg * Hn + jl] : 0.f;
      Bx[r] = f2bf(v);
    }
  }
}

// Two fused recurrent steps. Grid 256 = 16 bb x 16 l-chunks (32 rows owned).
// 640 threads (10 waves); wave w owns n-tiles {w, w+10, w+20} = r/z/n gates
// for j in [16w, 16w+16).
__global__ __launch_bounds__(640)
void gru_pair(const short* __restrict__ hbin, short* __restrict__ hbout,
              float* __restrict__ hf, const short* __restrict__ Bh,
              const short* __restrict__ Bx, const float* __restrict__ xs, int t) {
  __shared__ short awh [52 * 168];   // h_t window rows l0-10..l0+41 (17.1 KB)
  __shared__ short awh2[36 * 168];   // h_{t+1} window rows l0-2..l0+33 (11.8 KB)
  __shared__ short awx [52 * 72];    // xs(t)   window (7.3 KB)
  __shared__ short awx2[36 * 72];    // xs(t+1) window (5.1 KB)
  __shared__ float h1l [32 * H1S];   // fp32 h_{t+1}, owned rows (20.5 KB)
  const int tid = threadIdx.x;
  const int bb  = blockIdx.x >> 4;
  const int l0  = (blockIdx.x & 15) << 5;

  // ---- staging (simple interleaved, proven in r5) ----
  for (int i = tid; i < 52 * 40; i += 640) {
    int r = i / 40, c4 = (i - r * 40) * 4;
    int l = l0 - 10 + r;
    s16x4 v = {0, 0, 0, 0};
    if (l >= 0 && l < Ln) v = *(const s16x4*)&hbin[((size_t)bb * Ln + l) * HP + c4];
    *(s16x4*)&awh[r * 168 + c4] = v;
  }
  for (int i = tid; i < 52 * 16; i += 640) {
    int r = i >> 4, c4 = (i & 15) * 4;
    int l = l0 - 10 + r;
    s16x4 v = {0, 0, 0, 0};
    if (l >= 0 && l < Ln) {
      f32x4 f = *(const f32x4*)&xs[(((size_t)bb * Tn + t) * Ln + l) * Cn + c4];
      v[0] = f2bf(f[0]); v[1] = f2bf(f[1]); v[2] = f2bf(f[2]); v[3] = f2bf(f[3]);
    }
    *(s16x4*)&awx[r * 72 + c4] = v;
  }
  for (int i = tid; i < 36 * 16; i += 640) {
    int r = i >> 4, c4 = (i & 15) * 4;
    int l = l0 - 2 + r;
    s16x4 v = {0, 0, 0, 0};
    if (l >= 0 && l < Ln) {
      f32x4 f = *(const f32x4*)&xs[(((size_t)bb * Tn + t + 1) * Ln + l) * Cn + c4];
      v[0] = f2bf(f[0]); v[1] = f2bf(f[1]); v[2] = f2bf(f[2]); v[3] = f2bf(f[3]);
    }
    *(s16x4*)&awx2[r * 72 + c4] = v;
  }
  // zero awh2 pad channels 150..159 (uninitialized LDS could be NaN; NaN*0=NaN)
  if (tid < 360) {
    int r = tid / 10, c = tid - r * 10;
    awh2[r * 168 + 150 + c] = 0;
  }
  __syncthreads();

  const int lane = tid & 63, w = tid >> 6;
  const int quad = lane >> 4, l16 = lane & 15;
  const int j = w * 16 + l16;

  const short* Bph[3];
  const short* Bpx[3];
#pragma unroll
  for (int g = 0; g < 3; ++g) {
    Bph[g] = Bh + (size_t)(w + 10 * g) * (KCH * 512) + lane * 8;
    Bpx[g] = Bx + (size_t)(w + 10 * g) * (KCX * 512) + lane * 8;
  }
  const int arh = l16 * 168 + quad * 8;
  const int arx = l16 * 72 + quad * 8;

  // ================= STEP 1: 48 rows (3 m-frags), out rows o = l-l0+8 =======
  f32x4 acc[3][3] = {};   // r | z | n(h-part)
  f32x4 axn[3] = {};      // n(x-part)
  {
    bf16x8 bh[3][3], bx[3][3];
#pragma unroll
    for (int s = 0; s < 2; ++s)
#pragma unroll
      for (int g = 0; g < 3; ++g) bh[s][g] = *(const bf16x8*)(Bph[g] + s * 512);

#pragma unroll
    for (int kc = 0; kc < KCH; ++kc) {
      const int cur = kc % 3;
      if (kc + 2 < KCH) {
        const int nxt = (kc + 2) % 3;
#pragma unroll
        for (int g = 0; g < 3; ++g)
          bh[nxt][g] = *(const bf16x8*)(Bph[g] + (kc + 2) * 512);
      }
      if (kc == KCH - 3) {
#pragma unroll
        for (int g = 0; g < 3; ++g) bx[0][g] = *(const bf16x8*)(Bpx[g]);
      }
      if (kc == KCH - 2) {
#pragma unroll
        for (int g = 0; g < 3; ++g) bx[1][g] = *(const bf16x8*)(Bpx[g] + 512);
      }
      const int kk = kc / 5, jj = (kc - kk * 5) * 32;
      const short* ar = &awh[arh + kk * 168 + jj];
      bf16x8 a0 = *(const bf16x8*)(ar);
      bf16x8 a1 = *(const bf16x8*)(ar + 16 * 168);
      bf16x8 a2 = *(const bf16x8*)(ar + 32 * 168);
#pragma unroll
      for (int g = 0; g < 3; ++g) {
        acc[0][g] = __builtin_amdgcn_mfma_f32_16x16x32_bf16(a0, bh[cur][g], acc[0][g], 0, 0, 0);
        acc[1][g] = __builtin_amdgcn_mfma_f32_16x16x32_bf16(a1, bh[cur][g], acc[1][g], 0, 0, 0);
        acc[2][g] = __builtin_amdgcn_mfma_f32_16x16x32_bf16(a2, bh[cur][g], acc[2][g], 0, 0, 0);
      }
    }
#pragma unroll
    for (int kc = 0; kc < KCX; ++kc) {
      const int cur = kc % 3;
      if (kc + 2 < KCX) {
        const int nxt = (kc + 2) % 3;
#pragma unroll
        for (int g = 0; g < 3; ++g)
          bx[nxt][g] = *(const bf16x8*)(Bpx[g] + (kc + 2) * 512);
      }
      const int kk = kc >> 1, jj = (kc & 1) * 32;
      const short* ar = &awx[arx + kk * 72 + jj];
      bf16x8 a0 = *(const bf16x8*)(ar);
      bf16x8 a1 = *(const bf16x8*)(ar + 16 * 72);
      bf16x8 a2 = *(const bf16x8*)(ar + 32 * 72);
      acc[0][0] = __builtin_amdgcn_mfma_f32_16x16x32_bf16(a0, bx[cur][0], acc[0][0], 0, 0, 0);
      acc[1][0] = __builtin_amdgcn_mfma_f32_16x16x32_bf16(a1, bx[cur][0], acc[1][0], 0, 0, 0);
      acc[2][0] = __builtin_amdgcn_mfma_f32_16x16x32_bf16(a2, bx[cur][0], acc[2][0], 0, 0, 0);
      acc[0][1] = __builtin_amdgcn_mfma_f32_16x16x32_bf16(a0, bx[cur][1], acc[0][1], 0, 0, 0);
      acc[1][1] = __builtin_amdgcn_mfma_f32_16x16x32_bf16(a1, bx[cur][1], acc[1][1], 0, 0, 0);
      acc[2][1] = __builtin_amdgcn_mfma_f32_16x16x32_bf16(a2, bx[cur][1], acc[2][1], 0, 0, 0);
      axn[0]    = __builtin_amdgcn_mfma_f32_16x16x32_bf16(a0, bx[cur][2], axn[0], 0, 0, 0);
      axn[1]    = __builtin_amdgcn_mfma_f32_16x16x32_bf16(a1, bx[cur][2], axn[1], 0, 0, 0);
      axn[2]    = __builtin_amdgcn_mfma_f32_16x16x32_bf16(a2, bx[cur][2], axn[2], 0, 0, 0);
    }
  }

  // ---- epilogue 1: h_{t+1}; own rows -> h1l fp32; rows l0-2..l0+33 -> awh2 bf16
  if (j < Hn) {
#pragma unroll
    for (int mi = 0; mi < 3; ++mi)
#pragma unroll
      for (int r = 0; r < 4; ++r) {
        const int o = mi * 16 + quad * 4 + r;   // out row in [0,48)
        const int l = l0 - 8 + o;
        const bool own = (o >= 8 && o < 40);
        float ho;
        if (own) ho = hf[((size_t)bb * Ln + l) * Hn + j];
        else     ho = bf2f(awh[(o + 2) * 168 + j]);   // halo (OOB rows are 0)
        float rg = 1.f / (1.f + __expf(-acc[mi][0][r]));
        float zg = 1.f / (1.f + __expf(-acc[mi][1][r]));
        float xg = axn[mi][r] + rg * acc[mi][2][r];
        xg = fminf(fmaxf(xg, -15.f), 15.f);
        float e = __expf(2.f * xg);
        float n = (e - 1.f) / (e + 1.f);
        float h1 = (1.f - zg) * n + zg * ho;
        if (o >= 6 && o < 42)
          awh2[(o - 6) * 168 + j] = (l >= 0 && l < Ln) ? f2bf(h1) : (short)0;
        if (own) h1l[(o - 8) * H1S + j] = h1;
      }
  }
  __syncthreads();

  // ================= STEP 2: 32 owned rows (2 m-frags) ======================
  f32x4 acc2[2][3] = {};
  f32x4 axn2[2] = {};
  {
    bf16x8 bh[3][3], bx[3][3];
#pragma unroll
    for (int s = 0; s < 2; ++s)
#pragma unroll
      for (int g = 0; g < 3; ++g) bh[s][g] = *(const bf16x8*)(Bph[g] + s * 512);

#pragma unroll
    for (int kc = 0; kc < KCH; ++kc) {
      const int cur = kc % 3;
      if (kc + 2 < KCH) {
        const int nxt = (kc + 2) % 3;
#pragma unroll
        for (int g = 0; g < 3; ++g)
          bh[nxt][g] = *(const bf16x8*)(Bph[g] + (kc + 2) * 512);
      }
      if (kc == KCH - 3) {
#pragma unroll
        for (int g = 0; g < 3; ++g) bx[0][g] = *(const bf16x8*)(Bpx[g]);
      }
      if (kc == KCH - 2) {
#pragma unroll
        for (int g = 0; g < 3; ++g) bx[1][g] = *(const bf16x8*)(Bpx[g] + 512);
      }
      const int kk = kc / 5, jj = (kc - kk * 5) * 32;
      const short* ar = &awh2[arh + kk * 168 + jj];
      bf16x8 a0 = *(const bf16x8*)(ar);
      bf16x8 a1 = *(const bf16x8*)(ar + 16 * 168);
#pragma unroll
      for (int g = 0; g < 3; ++g) {
        acc2[0][g] = __builtin_amdgcn_mfma_f32_16x16x32_bf16(a0, bh[cur][g], acc2[0][g], 0, 0, 0);
        acc2[1][g] = __builtin_amdgcn_mfma_f32_16x16x32_bf16(a1, bh[cur][g], acc2[1][g], 0, 0, 0);
      }
    }
#pragma unroll
    for (int kc = 0; kc < KCX; ++kc) {
      const int cur = kc % 3;
      if (kc + 2 < KCX) {
        const int nxt = (kc + 2) % 3;
#pragma unroll
        for (int g = 0; g < 3; ++g)
          bx[nxt][g] = *(const bf16x8*)(Bpx[g] + (kc + 2) * 512);
      }
      const int kk = kc >> 1, jj = (kc & 1) * 32;
      const short* ar = &awx2[arx + kk * 72 + jj];
      bf16x8 a0 = *(const bf16x8*)(ar);
      bf16x8 a1 = *(const bf16x8*)(ar + 16 * 72);
      acc2[0][0] = __builtin_amdgcn_mfma_f32_16x16x32_bf16(a0, bx[cur][0], acc2[0][0], 0, 0, 0);
      acc2[1][0] = __builtin_amdgcn_mfma_f32_16x16x32_bf16(a1, bx[cur][0], acc2[1][0], 0, 0, 0);
      acc2[0][1] = __builtin_amdgcn_mfma_f32_16x16x32_bf16(a0, bx[cur][1], acc2[0][1], 0, 0, 0);
      acc2[1][1] = __builtin_amdgcn_mfma_f32_16x16x32_bf16(a1, bx[cur][1], acc2[1][1], 0, 0, 0);
      axn2[0]    = __builtin_amdgcn_mfma_f32_16x16x32_bf16(a0, bx[cur][2], axn2[0], 0, 0, 0);
      axn2[1]    = __builtin_amdgcn_mfma_f32_16x16x32_bf16(a1, bx[cur][2], axn2[1], 0, 0, 0);
    }
  }

  // ---- epilogue 2: h_{t+2} for owned rows -> hf (fp32) + hbout (bf16) ----
  if (j < Hn) {
#pragma unroll
    for (int mi = 0; mi < 2; ++mi)
#pragma unroll
      for (int r = 0; r < 4; ++r) {
        const int o2 = mi * 16 + quad * 4 + r;   // owned row in [0,32)
        const size_t mrow = (size_t)bb * Ln + l0 + o2;
        float ho = h1l[o2 * H1S + j];
        float rg = 1.f / (1.f + __expf(-acc2[mi][0][r]));
        float zg = 1.f / (1.f + __expf(-acc2[mi][1][r]));
        float xg = axn2[mi][r] + rg * acc2[mi][2][r];
        xg = fminf(fmaxf(xg, -15.f), 15.f);
        float e = __expf(2.f * xg);
        float n = (e - 1.f) / (e + 1.f);
        float h2 = (1.f - zg) * n + zg * ho;
        hf[mrow * Hn + j] = h2;
        hbout[mrow * HP + j] = f2bf(h2);
      }
  }
}

// Head: thread-per-output fp32.
__global__ __launch_bounds__(256) void head1(const float* __restrict__ hf,
                                             const float* __restrict__ W1,
                                             const float* __restrict__ b1,
                                             float* __restrict__ hdn) {
  int idx = blockIdx.x * 256 + threadIdx.x;
  if (idx >= Mtot * Hn) return;
  int m = idx / Hn, j = idx - m * Hn;
  const float* hr = hf + (size_t)m * Hn;
  float acc = b1[j];
#pragma unroll 10
  for (int i = 0; i < Hn; ++i) acc = fmaf(hr[i], W1[i * Hn + j], acc);
  hdn[idx] = acc / (1.f + __expf(-acc));   // silu
}
__global__ __launch_bounds__(256) void head2(const float* __restrict__ hdn,
                                             const float* __restrict__ W2,
                                             const float* __restrict__ b2,
                                             float* __restrict__ out) {
  int idx = blockIdx.x * 256 + threadIdx.x;
  if (idx >= Mtot * 24) return;
  int m = idx / 24, j = idx - m * 24;
  const float* hr = hdn + (size_t)m * Hn;
  float acc = b2[j];
#pragma unroll 10
  for (int i = 0; i < Hn; ++i) acc = fmaf(hr[i], W2[i * 24 + j], acc);
  out[idx] = acc;
}

extern "C" void kernel_launch(void* const* d_in, const int* in_sizes, int n_in,
                              void* d_out, int out_size, void* d_ws, size_t ws_size,
                              hipStream_t stream) {
  const float* xs = (const float*)d_in[0];
  const float* ki = (const float*)d_in[1];
  const float* kh = (const float*)d_in[2];
  const float* W1 = (const float*)d_in[3];
  const float* b1 = (const float*)d_in[4];
  const float* W2 = (const float*)d_in[5];
  const float* b2 = (const float*)d_in[6];
  float* out = (float*)d_out;

  char* p = (char*)d_ws;
  float* hf  = (float*)p; p += (size_t)Mtot * Hn * 4;       // 4.7 MiB
  float* hdn = (float*)p; p += (size_t)Mtot * Hn * 4;       // 4.7 MiB
  short* hbA = (short*)p; p += (size_t)Mtot * HP * 2;       // 2.5 MiB
  short* hbB = (short*)p; p += (size_t)Mtot * HP * 2;       // 2.5 MiB
  short* Bh  = (short*)p; p += (size_t)32 * KCH * 512 * 2;  // 0.8 MiB
  short* Bx  = (short*)p; p += (size_t)32 * KCX * 512 * 2;  // 0.3 MiB

  hipMemsetAsync(hf, 0, (size_t)Mtot * Hn * 4, stream);
  hipMemsetAsync(hbA, 0, (size_t)Mtot * HP * 2 * 2, stream);  // both buffers; pads stay 0
  pack_weights<<<(32 * (KCH + KCX) * 512 + 255) / 256, 256, 0, stream>>>(ki, kh, Bx, Bh);

  for (int k = 0; k < 32; ++k) {
    short* hin  = (k & 1) ? hbB : hbA;
    short* hout = (k & 1) ? hbA : hbB;
    gru_pair<<<256, 640, 0, stream>>>(hin, hout, hf, Bh, Bx, xs, 2 * k);
  }
  head1<<<(Mtot * Hn + 255) / 256, 256, 0, stream>>>(hf, W1, b1, hdn);
  head2<<<(Mtot * 24 + 255) / 256, 256, 0, stream>>>(hdn, W2, b2, out);
}

// Round 3
// 1457.315 us; speedup vs baseline: 1.5451x; 1.5451x over previous
//
#include <hip/hip_runtime.h>

// GlobalNet conv-GRU on MI355X — round 8.
// r7 post-mortem: VGPR_Count=84 + 38.7MB WRITE/dispatch = rolling-prefetch
// arrays demoted to scratch (4 unrolled K-loops blew the pressure budget).
// RECOVERY: restore r5's exact single-step kernel shape (proven 19.8us/step
// codegen: acc[2][3]+axn[2], bh[4][3], bx[3][3], 640 thr, 64 launches).
// ONE change: wave->work map. 256 blocks = 128 m-blocks (M=64) x 2 N-halves;
// 10 waves = 2 m-halves x 5 j-tiles. Twin waves (w, w+5) stream the SAME
// three packed-B slices in lockstep on one CU -> second read served by L1,
// cutting the dominant B-from-L2 term (~8us/step at M=32). Plus: epilogue hf
// reads hoisted to a burst before the x-GEMM (latency hidden under 60 MFMAs).

#define Bn   16
#define Tn   64
#define Ln   512
#define Cn   64
#define Hn   150
#define G3   450
#define SW   160
#define HP   160    // padded hidden
#define KCH  25     // k-chunks (32) for h GEMM (K=800)
#define KCX  10     // k-chunks for x GEMM (K=320)
#define Mtot 8192   // Bn*Ln

typedef __bf16 bf16x8 __attribute__((ext_vector_type(8)));
typedef float  f32x4  __attribute__((ext_vector_type(4)));
typedef short  s16x4  __attribute__((ext_vector_type(4)));

__device__ inline short f2bf(float f) {
  unsigned u = __builtin_bit_cast(unsigned, f);
  u += 0x7fffu + ((u >> 16) & 1u);   // RNE (finite inputs)
  return (short)(u >> 16);
}

// Packed B layout: [nt (n/16)][kc][lane (quad*16+l16)][j (8)] shorts.
// Fragment element: B[k = kc*32+quad*8+j][n = nt*16+l16].
// n maps (seg=n/160, jl=n%160) -> orig col seg*150+jl (zero pad elsewhere).
__global__ __launch_bounds__(256) void pack_weights(const float* __restrict__ ki,
                                                    const float* __restrict__ kh,
                                                    short* __restrict__ Bx,
                                                    short* __restrict__ Bh) {
  int idx = blockIdx.x * 256 + threadIdx.x;
  if (idx < 32 * KCH * 512) {
    int j = idx & 7, lane = (idx >> 3) & 63;
    int rest = idx >> 9;
    int kc = rest % KCH, nt = rest / KCH;
    int quad = lane >> 4, l16 = lane & 15;
    int n = nt * 16 + l16, seg = n / SW, jl = n - seg * SW;
    int kk = kc / 5, jj = (kc - kk * 5) * 32 + quad * 8 + j;
    float v = (seg < 3 && jl < Hn && jj < Hn) ? kh[(kk * Hn + jj) * G3 + seg * Hn + jl] : 0.f;
    Bh[idx] = f2bf(v);
  } else {
    int r = idx - 32 * KCH * 512;
    if (r < 32 * KCX * 512) {
      int j = r & 7, lane = (r >> 3) & 63;
      int rest = r >> 9;
      int kc = rest % KCX, nt = rest / KCX;
      int quad = lane >> 4, l16 = lane & 15;
      int n = nt * 16 + l16, seg = n / SW, jl = n - seg * SW;
      int kk = kc / 2, cc = (kc - kk * 2) * 32 + quad * 8 + j;
      float v = (seg < 3 && jl < Hn) ? ki[(kk * Cn + cc) * G3 + seg * Hn + jl] : 0.f;
      Bx[r] = f2bf(v);
    }
  }
}

// One recurrent step. Grid 256 = 128 m-blocks (bb = mb/8, l0 = (mb%8)*64,
// M = 64 rows) x 2 N-halves (ns). 640 threads (10 waves): wave w -> m-half
// mh = w/5, j-tile jt = w%5. Wave owns n-tiles {ns*5+jt+10g} (r/z/n gates)
// for rows l0+mh*32 .. +31. Twins (w, w+5) share B slices -> L1 hit.
__global__ __launch_bounds__(640)
void gru_step(const short* __restrict__ hbin, short* __restrict__ hbout,
              float* __restrict__ hf, const short* __restrict__ Bh,
              const short* __restrict__ Bx, const float* __restrict__ xs, int t) {
  __shared__ short awh[68 * 168];   // h window rows l0-2..l0+65, 160 ch (22.8 KB)
  __shared__ short awx[68 * 72];    // x window, 64 ch (9.8 KB)
  const int tid = threadIdx.x;
  const int ns  = blockIdx.x & 1;
  const int mb  = blockIdx.x >> 1;
  const int bb  = mb >> 3;
  const int l0  = (mb & 7) << 6;

  for (int i = tid; i < 68 * 40; i += 640) {
    int r = i / 40, c4 = (i - r * 40) * 4;
    int l = l0 - 2 + r;
    s16x4 v = {0, 0, 0, 0};
    if (l >= 0 && l < Ln) v = *(const s16x4*)&hbin[((size_t)bb * Ln + l) * HP + c4];
    *(s16x4*)&awh[r * 168 + c4] = v;
  }
  for (int i = tid; i < 68 * 16; i += 640) {
    int r = i >> 4, c4 = (i & 15) * 4;
    int l = l0 - 2 + r;
    s16x4 v = {0, 0, 0, 0};
    if (l >= 0 && l < Ln) {
      f32x4 f = *(const f32x4*)&xs[(((size_t)bb * Tn + t) * Ln + l) * Cn + c4];
      v[0] = f2bf(f[0]); v[1] = f2bf(f[1]); v[2] = f2bf(f[2]); v[3] = f2bf(f[3]);
    }
    *(s16x4*)&awx[r * 72 + c4] = v;
  }
  __syncthreads();

  const int lane = tid & 63, w = tid >> 6;
  const int quad = lane >> 4, l16 = lane & 15;
  const int mh = w / 5, jt = w - mh * 5;   // m-half, j-tile

  const short* Bph[3];
  const short* Bpx[3];
#pragma unroll
  for (int g = 0; g < 3; ++g) {
    const int nt = ns * 5 + jt + 10 * g;
    Bph[g] = Bh + (size_t)nt * (KCH * 512) + lane * 8;
    Bpx[g] = Bx + (size_t)nt * (KCX * 512) + lane * 8;
  }
  const int arh = (mh * 32 + l16) * 168 + quad * 8;
  const int arx = (mh * 32 + l16) * 72 + quad * 8;

  f32x4 acc[2][3] = {};   // r | z | n(h-part)
  f32x4 axn[2] = {};      // n(x-part), kept separate: n = tanh(iin + r*hin)

  // Prime x-phase B loads early (independent of the h loop — deep in flight).
  bf16x8 bx[3][3];
#pragma unroll
  for (int s = 0; s < 2; ++s)
#pragma unroll
    for (int g = 0; g < 3; ++g) bx[s][g] = *(const bf16x8*)(Bpx[g] + s * 512);

  bf16x8 bh[4][3];   // 4-stage rolling prefetch
#pragma unroll
  for (int s = 0; s < 3; ++s)
#pragma unroll
    for (int g = 0; g < 3; ++g) bh[s][g] = *(const bf16x8*)(Bph[g] + s * 512);

#pragma unroll
  for (int kc = 0; kc < KCH; ++kc) {
    const int cur = kc & 3;
    if (kc + 3 < KCH) {
      const int nxt = (kc + 3) & 3;
#pragma unroll
      for (int g = 0; g < 3; ++g)
        bh[nxt][g] = *(const bf16x8*)(Bph[g] + (kc + 3) * 512);
    }
    const int kk = kc / 5, jj = (kc - kk * 5) * 32;
    const short* ar = &awh[arh + kk * 168 + jj];
    bf16x8 a0 = *(const bf16x8*)(ar);
    bf16x8 a1 = *(const bf16x8*)(ar + 16 * 168);
#pragma unroll
    for (int g = 0; g < 3; ++g) {
      acc[0][g] = __builtin_amdgcn_mfma_f32_16x16x32_bf16(a0, bh[cur][g], acc[0][g], 0, 0, 0);
      acc[1][g] = __builtin_amdgcn_mfma_f32_16x16x32_bf16(a1, bh[cur][g], acc[1][g], 0, 0, 0);
    }
  }

  // Hoisted epilogue h_old reads: independent of the x-GEMM below, so the
  // ~500cy global latency hides under its 60 MFMAs.
  const int j = ns * 80 + jt * 16 + l16;
  float hold[2][4];
  if (j < Hn) {
#pragma unroll
    for (int mi = 0; mi < 2; ++mi)
#pragma unroll
      for (int r = 0; r < 4; ++r) {
        const int ml = mh * 32 + mi * 16 + quad * 4 + r;
        hold[mi][r] = hf[((size_t)bb * Ln + l0 + ml) * Hn + j];
      }
  }

#pragma unroll
  for (int kc = 0; kc < KCX; ++kc) {
    const int cur = kc % 3;
    if (kc + 2 < KCX) {
      const int nxt = (kc + 2) % 3;
#pragma unroll
      for (int g = 0; g < 3; ++g)
        bx[nxt][g] = *(const bf16x8*)(Bpx[g] + (kc + 2) * 512);
    }
    const int kk = kc >> 1, jj = (kc & 1) * 32;
    const short* ar = &awx[arx + kk * 72 + jj];
    bf16x8 a0 = *(const bf16x8*)(ar);
    bf16x8 a1 = *(const bf16x8*)(ar + 16 * 72);
    acc[0][0] = __builtin_amdgcn_mfma_f32_16x16x32_bf16(a0, bx[cur][0], acc[0][0], 0, 0, 0);
    acc[1][0] = __builtin_amdgcn_mfma_f32_16x16x32_bf16(a1, bx[cur][0], acc[1][0], 0, 0, 0);
    acc[0][1] = __builtin_amdgcn_mfma_f32_16x16x32_bf16(a0, bx[cur][1], acc[0][1], 0, 0, 0);
    acc[1][1] = __builtin_amdgcn_mfma_f32_16x16x32_bf16(a1, bx[cur][1], acc[1][1], 0, 0, 0);
    axn[0]    = __builtin_amdgcn_mfma_f32_16x16x32_bf16(a0, bx[cur][2], axn[0], 0, 0, 0);
    axn[1]    = __builtin_amdgcn_mfma_f32_16x16x32_bf16(a1, bx[cur][2], axn[1], 0, 0, 0);
  }

  // Gates: lane covers j = ns*80 + jt*16 + l16, rows ml = mh*32 + mi*16 + quad*4 + r.
  if (j < Hn) {
#pragma unroll
    for (int mi = 0; mi < 2; ++mi)
#pragma unroll
      for (int r = 0; r < 4; ++r) {
        const int ml = mh * 32 + mi * 16 + quad * 4 + r;
        const size_t mrow = (size_t)bb * Ln + l0 + ml;
        float rg = 1.f / (1.f + __expf(-acc[mi][0][r]));
        float zg = 1.f / (1.f + __expf(-acc[mi][1][r]));
        float xg = axn[mi][r] + rg * acc[mi][2][r];
        xg = fminf(fmaxf(xg, -15.f), 15.f);
        float e = __expf(2.f * xg);
        float n = (e - 1.f) / (e + 1.f);
        float hn = (1.f - zg) * n + zg * hold[mi][r];
        hf[mrow * Hn + j] = hn;
        hbout[mrow * HP + j] = f2bf(hn);
      }
  }
}

// Head: thread-per-output fp32.
__global__ __launch_bounds__(256) void head1(const float* __restrict__ hf,
                                             const float* __restrict__ W1,
                                             const float* __restrict__ b1,
                                             float* __restrict__ hdn) {
  int idx = blockIdx.x * 256 + threadIdx.x;
  if (idx >= Mtot * Hn) return;
  int m = idx / Hn, j = idx - m * Hn;
  const float* hr = hf + (size_t)m * Hn;
  float acc = b1[j];
#pragma unroll 10
  for (int i = 0; i < Hn; ++i) acc = fmaf(hr[i], W1[i * Hn + j], acc);
  hdn[idx] = acc / (1.f + __expf(-acc));   // silu
}
__global__ __launch_bounds__(256) void head2(const float* __restrict__ hdn,
                                             const float* __restrict__ W2,
                                             const float* __restrict__ b2,
                                             float* __restrict__ out) {
  int idx = blockIdx.x * 256 + threadIdx.x;
  if (idx >= Mtot * 24) return;
  int m = idx / 24, j = idx - m * 24;
  const float* hr = hdn + (size_t)m * Hn;
  float acc = b2[j];
#pragma unroll 10
  for (int i = 0; i < Hn; ++i) acc = fmaf(hr[i], W2[i * 24 + j], acc);
  out[idx] = acc;
}

extern "C" void kernel_launch(void* const* d_in, const int* in_sizes, int n_in,
                              void* d_out, int out_size, void* d_ws, size_t ws_size,
                              hipStream_t stream) {
  const float* xs = (const float*)d_in[0];
  const float* ki = (const float*)d_in[1];
  const float* kh = (const float*)d_in[2];
  const float* W1 = (const float*)d_in[3];
  const float* b1 = (const float*)d_in[4];
  const float* W2 = (const float*)d_in[5];
  const float* b2 = (const float*)d_in[6];
  float* out = (float*)d_out;

  char* p = (char*)d_ws;
  float* hf  = (float*)p; p += (size_t)Mtot * Hn * 4;       // 4.7 MiB
  float* hdn = (float*)p; p += (size_t)Mtot * Hn * 4;       // 4.7 MiB
  short* hbA = (short*)p; p += (size_t)Mtot * HP * 2;       // 2.5 MiB
  short* hbB = (short*)p; p += (size_t)Mtot * HP * 2;       // 2.5 MiB
  short* Bh  = (short*)p; p += (size_t)32 * KCH * 512 * 2;  // 0.8 MiB
  short* Bx  = (short*)p; p += (size_t)32 * KCX * 512 * 2;  // 0.3 MiB

  hipMemsetAsync(hf, 0, (size_t)Mtot * Hn * 4, stream);
  hipMemsetAsync(hbA, 0, (size_t)Mtot * HP * 2 * 2, stream);  // both buffers; pads stay 0
  pack_weights<<<(32 * (KCH + KCX) * 512 + 255) / 256, 256, 0, stream>>>(ki, kh, Bx, Bh);

  for (int t = 0; t < Tn; ++t) {
    short* hin  = (t & 1) ? hbB : hbA;
    short* hout = (t & 1) ? hbA : hbB;
    gru_step<<<256, 640, 0, stream>>>(hin, hout, hf, Bh, Bx, xs, t);
  }
  head1<<<(Mtot * Hn + 255) / 256, 256, 0, stream>>>(hf, W1, b1, hdn);
  head2<<<(Mtot * 24 + 255) / 256, 256, 0, stream>>>(hdn, W2, b2, out);
}